// Round 11
// baseline (199.256 us; speedup 1.0000x reference)
//
#include <hip/hip_runtime.h>

#define BB 32
#define OO 64
#define II 64
#define FF 16
#define HH 128
#define WW 128

typedef __attribute__((ext_vector_type(8))) __bf16 bf16x8;
typedef __attribute__((ext_vector_type(4))) float f32x4;

typedef __attribute__((address_space(3))) uint8_t  lds_u8;
typedef __attribute__((address_space(1))) const uint8_t g_u8;

// ---------------- Kernel 1: weight/bias generation ----------------
__global__ __launch_bounds__(64)
void gen_weights(const float* __restrict__ addr,
                 const float* __restrict__ w_bank,
                 const float* __restrict__ b_bank,
                 __bf16* __restrict__ wT,
                 float* __restrict__ bias_out) {
    const int bo  = blockIdx.x;            // b*64 + o
    const int tid = threadIdx.x;           // i = 0..63

    __shared__ float bank_s[FF * 9];
    __shared__ float bbank_s[FF];
    for (int idx = tid; idx < FF * 9; idx += 64) bank_s[idx] = w_bank[idx];
    if (tid < FF) bbank_s[tid] = b_bank[tid];
    __syncthreads();

    const float* arow = addr + ((size_t)bo * (II + 1) + 1 + tid) * FF;
    float a[FF];
    float m = -1e30f;
#pragma unroll
    for (int f = 0; f < FF; ++f) { a[f] = arow[f]; m = fmaxf(m, a[f]); }
    float s = 0.f;
#pragma unroll
    for (int f = 0; f < FF; ++f) { a[f] = __expf(a[f] - m); s += a[f]; }
    const float inv = 1.0f / s;

    const int b = bo >> 6, o = bo & 63;
#pragma unroll
    for (int kl = 0; kl < 9; ++kl) {
        float acc = 0.f;
#pragma unroll
        for (int f = 0; f < FF; ++f) acc += a[f] * bank_s[f * 9 + kl];
        wT[(((size_t)b * 9 + kl) * OO + o) * II + tid] = (__bf16)(acc * inv);
    }

    if (tid == 0) {
        const float* brow = addr + (size_t)bo * (II + 1) * FF;
        float bb[FF];
        float bm = -1e30f;
#pragma unroll
        for (int f = 0; f < FF; ++f) { bb[f] = brow[f]; bm = fmaxf(bm, bb[f]); }
        float bs = 0.f;
#pragma unroll
        for (int f = 0; f < FF; ++f) { bb[f] = __expf(bb[f] - bm); bs += bb[f]; }
        float acc = 0.f;
#pragma unroll
        for (int f = 0; f < FF; ++f) acc += bb[f] * bbank_s[f];
        bias_out[bo] = acc / bs;
    }
}

// ---------------- Kernel 2: fused transpose + implicit-GEMM conv ----------------
// 512 threads (8 waves), LDS = ring only (67.6KB). Grid = 256 (1 block/CU).
// __launch_bounds__(512, 1): HIP's 2nd arg is min BLOCKS/CU (CUDA semantics;
// measured: (512,4)->cap 64 VGPR, (512,2)->cap 128) -> arg 1 gives the
// 256-VGPR cap that the 144-VGPR register-resident A tile needs.
// Block: (b, px-half, 32-row group), 16 phases of {2 rows x 64 px x 64 o}.
// A loaded from global ONCE (L2-hot), pinned via asm; inner loop reads only
// B from LDS (36 ds_read_b128/phase/wave instead of R6's 72).
#define SLOTB 8448               // 66 px * 128 B
#define LDSZ (8 * SLOTB)         // 67584 B

// issue loads for ring pair q (padded local rows 2q, 2q+1) into sm0/sm1/smt
#define LOADPAIR(q_) do {                                                          \
    const int pxg_ = ph * 64 + l - 1;                                              \
    const bool okpx_ = (unsigned)pxg_ < 128u;                                      \
    _Pragma("unroll")                                                              \
    for (int j_ = 0; j_ < 2; ++j_) {                                               \
        const int rr_ = R0 + 2 * (q_) + j_ - 1;                                    \
        const bool ok_ = okpx_ && ((unsigned)rr_ < 128u);                          \
        const float* xs_ = xb + ((size_t)(wv * 8) * HH + rr_) * WW + pxg_;         \
        float* dst_ = j_ ? sm1 : sm0;                                              \
        _Pragma("unroll")                                                          \
        for (int jj_ = 0; jj_ < 8; ++jj_) {                                        \
            float v_ = 0.f;                                                        \
            if (ok_) v_ = xs_[(size_t)jj_ * (HH * WW)];                            \
            dst_[jj_] = v_;                                                        \
        }                                                                          \
    }                                                                              \
    {   /* tail: px 64,65 for both rows; lanes 0..31 of wave 0 */                  \
        const int lr_ = l >> 4;                                                    \
        const int cc_ = (l >> 1) & 7;                                              \
        const int pxl_ = 64 + (l & 1);                                             \
        const int pxg2_ = ph * 64 + pxl_ - 1;                                      \
        const int rr_ = R0 + 2 * (q_) + lr_ - 1;                                   \
        const bool ok_ = (t < 32) && ((unsigned)pxg2_ < 128u)                      \
                         && ((unsigned)rr_ < 128u);                                \
        const float* xs_ = xb + ((size_t)(cc_ * 8) * HH + rr_) * WW + pxg2_;       \
        _Pragma("unroll")                                                          \
        for (int jj_ = 0; jj_ < 8; ++jj_) {                                        \
            float v_ = 0.f;                                                        \
            if (ok_) v_ = xs_[(size_t)jj_ * (HH * WW)];                            \
            smt[jj_] = v_;                                                         \
        }                                                                          \
    }                                                                              \
} while (0)

// convert + ds_write pair q (implicit vmcnt wait on sm* uses)
#define WRITEPAIR(q_) do {                                                         \
    bf16x8 u_;                                                                     \
    _Pragma("unroll")                                                              \
    for (int jj_ = 0; jj_ < 8; ++jj_) u_[jj_] = (__bf16)sm0[jj_];                  \
    *(bf16x8*)(LDS + ((2 * (q_)) & 7) * SLOTB + l * 128                            \
               + ((wv ^ (l & 7)) << 4)) = u_;                                      \
    _Pragma("unroll")                                                              \
    for (int jj_ = 0; jj_ < 8; ++jj_) u_[jj_] = (__bf16)sm1[jj_];                  \
    *(bf16x8*)(LDS + ((2 * (q_) + 1) & 7) * SLOTB + l * 128                        \
               + ((wv ^ (l & 7)) << 4)) = u_;                                      \
    if (t < 32) {                                                                  \
        const int lr_ = l >> 4;                                                    \
        const int cc_ = (l >> 1) & 7;                                              \
        const int pxl_ = 64 + (l & 1);                                             \
        _Pragma("unroll")                                                          \
        for (int jj_ = 0; jj_ < 8; ++jj_) u_[jj_] = (__bf16)smt[jj_];              \
        *(bf16x8*)(LDS + ((2 * (q_) + lr_) & 7) * SLOTB + pxl_ * 128               \
                   + ((cc_ ^ (pxl_ & 7)) << 4)) = u_;                              \
    }                                                                              \
} while (0)

__global__ __launch_bounds__(512, 1)
void conv_fused(const float* __restrict__ x, const __bf16* __restrict__ wT,
                const float* __restrict__ bias, float* __restrict__ y) {
    __shared__ __align__(16) char LDS[LDSZ];

    // bijective XCD swizzle: blocks of one batch share an XCD
    const int hwid = blockIdx.x;
    const int work = (hwid & 7) * 32 + (hwid >> 3);
    const int b  = work >> 3;
    const int r3 = work & 7;
    const int ph = r3 >> 2;                // px half (64 px)
    const int rg = r3 & 3;                 // 32-row group
    const int R0 = rg * 32;

    const int t  = threadIdx.x;
    const int wv = t >> 6;
    const int l  = t & 63;
    const int lm = l & 15;
    const int lk = l >> 4;
    const int oh = wv >> 2;                // o half (32 o)
    const int g  = wv & 3;                 // px-16 group within 64

    const __bf16* wb = wT + (size_t)b * 9 * OO * II;
    const float*  xb = x + (size_t)b * II * HH * WW;

    const int pxbase = g * 16 + lm;        // lane's local px (0..63)
    const int obase0 = oh * 32 + lm;       // lane's A row for mf=0

    float sm0[8], sm1[8], smt[8];

    // stage x ring pairs 0,1 (padded local rows 0..3)
    LOADPAIR(0);
    WRITEPAIR(0);
    LOADPAIR(1);
    WRITEPAIR(1);

    // ---- A fragments: global -> 144 VGPRs, once (L2-hot) ----
    bf16x8 Areg[9][2][2];                  // [kl][k0][mf]
#pragma unroll
    for (int kl = 0; kl < 9; ++kl)
#pragma unroll
        for (int k0 = 0; k0 < 2; ++k0)
#pragma unroll
            for (int mf = 0; mf < 2; ++mf)
                Areg[kl][k0][mf] = *(const bf16x8*)(wb
                    + ((size_t)(kl * 64 + obase0 + mf * 16) << 6) + k0 * 32 + lk * 8);
    // pin materialization here so the loads can't be sunk into the phase loop
#pragma unroll
    for (int kl = 0; kl < 9; ++kl)
#pragma unroll
        for (int k0 = 0; k0 < 2; ++k0)
#pragma unroll
            for (int mf = 0; mf < 2; ++mf)
                asm volatile("" : "+v"(Areg[kl][k0][mf]));

    // bias preload
    float bbias[2][4];
    {
        const float* bp = bias + b * OO;
#pragma unroll
        for (int mf = 0; mf < 2; ++mf)
#pragma unroll
            for (int r = 0; r < 4; ++r)
                bbias[mf][r] = bp[oh * 32 + mf * 16 + lk * 4 + r];
    }
    f32x4 acc[2][2];
#pragma unroll
    for (int mf = 0; mf < 2; ++mf)
#pragma unroll
        for (int nf = 0; nf < 2; ++nf)
#pragma unroll
            for (int r = 0; r < 4; ++r)
                acc[mf][nf][r] = bbias[mf][r];

    __syncthreads();                       // ring pairs 0,1 landed

    int s0 = 0;                            // slot base = (2p) & 7

    for (int p = 0; p < 16; ++p) {
        if (p < 15) LOADPAIR(p + 2);       // issue next pair's global loads

#pragma unroll
        for (int ks = 0; ks < 18; ++ks) {
            const int kl = ks >> 1, k0 = ks & 1;
            const int dr = kl / 3, dc = kl - 3 * dr;
            const int cc = lk + 4 * k0;    // logical 16B chunk of the k-slice
            bf16x8 bv[2];
            const int lpx = pxbase + dc;
#pragma unroll
            for (int nf = 0; nf < 2; ++nf) {
                const int slot = (s0 + nf + dr) & 7;
                const int baddr = slot * SLOTB + lpx * 128
                                + ((cc ^ (lpx & 7)) << 4);
                bv[nf] = *(const bf16x8*)(LDS + baddr);
            }
#pragma unroll
            for (int mf = 0; mf < 2; ++mf)
#pragma unroll
                for (int nf = 0; nf < 2; ++nf)
                    acc[mf][nf] = __builtin_amdgcn_mfma_f32_16x16x32_bf16(
                        Areg[kl][k0][mf], bv[nf], acc[mf][nf], 0, 0, 0);
        }

        if (p < 15) WRITEPAIR(p + 2);      // vmcnt waits land here, then ds_write

        __syncthreads();                   // ring rotated; next pair visible

        // stores + acc reinit (overlap next phase's loads)
#pragma unroll
        for (int mf = 0; mf < 2; ++mf)
#pragma unroll
            for (int r = 0; r < 4; ++r) {
                const int o = oh * 32 + mf * 16 + lk * 4 + r;
#pragma unroll
                for (int nf = 0; nf < 2; ++nf) {
                    const int rowg = R0 + 2 * p + nf;
                    y[(((size_t)b * OO + o) * HH + rowg) * WW + ph * 64 + pxbase]
                        = acc[mf][nf][r];
                }
            }
#pragma unroll
        for (int mf = 0; mf < 2; ++mf)
#pragma unroll
            for (int nf = 0; nf < 2; ++nf)
#pragma unroll
                for (int r = 0; r < 4; ++r)
                    acc[mf][nf][r] = bbias[mf][r];

        s0 = (s0 + 2) & 7;
    }
}

extern "C" void kernel_launch(void* const* d_in, const int* in_sizes, int n_in,
                              void* d_out, int out_size, void* d_ws, size_t ws_size,
                              hipStream_t stream) {
    const float* addresses = (const float*)d_in[0];   // (B,O,I+1,F)
    const float* x         = (const float*)d_in[1];   // (B,I,H,W)
    const float* w_bank    = (const float*)d_in[2];   // (F,3,3)
    const float* b_bank    = (const float*)d_in[3];   // (F,)
    float* out = (float*)d_out;                       // (B,O,H,W)

    // ws layout: [bias 8KB][wT 2.25MB]
    float*  bias_ws = (float*)d_ws;
    __bf16* wT      = (__bf16*)((char*)d_ws + 8192);

    gen_weights<<<BB * OO, 64, 0, stream>>>(addresses, w_bank, b_bank, wT, bias_ws);
    conv_fused<<<256, 512, 0, stream>>>(x, wT, bias_ws, out);
}

// Round 12
// 87.627 us; speedup vs baseline: 2.2739x; 2.2739x over previous
//
#include <hip/hip_runtime.h>

#define BB 32
#define OO 64
#define II 64
#define FF 16
#define HH 128
#define WW 128

typedef __attribute__((ext_vector_type(8))) __bf16 bf16x8;
typedef __attribute__((ext_vector_type(4))) float f32x4;

typedef __attribute__((address_space(3))) uint8_t  lds_u8;
typedef __attribute__((address_space(1))) const uint8_t g_u8;

// ---------------- Kernel 1: weight/bias generation ----------------
__global__ __launch_bounds__(64)
void gen_weights(const float* __restrict__ addr,
                 const float* __restrict__ w_bank,
                 const float* __restrict__ b_bank,
                 __bf16* __restrict__ wT,
                 float* __restrict__ bias_out) {
    const int bo  = blockIdx.x;            // b*64 + o
    const int tid = threadIdx.x;           // i = 0..63

    __shared__ float bank_s[FF * 9];
    __shared__ float bbank_s[FF];
    for (int idx = tid; idx < FF * 9; idx += 64) bank_s[idx] = w_bank[idx];
    if (tid < FF) bbank_s[tid] = b_bank[tid];
    __syncthreads();

    const float* arow = addr + ((size_t)bo * (II + 1) + 1 + tid) * FF;
    float a[FF];
    float m = -1e30f;
#pragma unroll
    for (int f = 0; f < FF; ++f) { a[f] = arow[f]; m = fmaxf(m, a[f]); }
    float s = 0.f;
#pragma unroll
    for (int f = 0; f < FF; ++f) { a[f] = __expf(a[f] - m); s += a[f]; }
    const float inv = 1.0f / s;

    const int b = bo >> 6, o = bo & 63;
#pragma unroll
    for (int kl = 0; kl < 9; ++kl) {
        float acc = 0.f;
#pragma unroll
        for (int f = 0; f < FF; ++f) acc += a[f] * bank_s[f * 9 + kl];
        wT[(((size_t)b * 9 + kl) * OO + o) * II + tid] = (__bf16)(acc * inv);
    }

    if (tid == 0) {
        const float* brow = addr + (size_t)bo * (II + 1) * FF;
        float bb[FF];
        float bm = -1e30f;
#pragma unroll
        for (int f = 0; f < FF; ++f) { bb[f] = brow[f]; bm = fmaxf(bm, bb[f]); }
        float bs = 0.f;
#pragma unroll
        for (int f = 0; f < FF; ++f) { bb[f] = __expf(bb[f] - bm); bs += bb[f]; }
        float acc = 0.f;
#pragma unroll
        for (int f = 0; f < FF; ++f) acc += bb[f] * bbank_s[f];
        bias_out[bo] = acc / bs;
    }
}

// ---------------- Kernel 2: fused transpose + implicit-GEMM conv ----------------
// 1024 threads (16 waves = 4/SIMD — 2x the TLP of the 512-thread variant),
// 1 block/CU, grid 256. Block: (b, px-half, 32-row group); 8 phases of
// {4 rows x 64 px x 64 o}. Wave = (oh, row r, px-32-group q): 2mf x 2nf.
// A (72KB) in LDS (shared by all 16 waves); x in a 10-slot ring (84.5KB).
// Staging split: waves 0-7 stage rows 4p+6,7; waves 8-15 rows 4p+8,9 —
// issued at phase start, ds_written at phase end (slots disjoint from the
// 6 live read slots), ONE barrier per phase. LDS total 158208 <= 160K.
#define SLOTB 8448               // 66 px * 128 B
#define NSLOT 10
#define RING  73728              // A region = [0, 73728)
#define LDSZ (RING + NSLOT * SLOTB)   // 158208 B

// load global x rows (prow p0_, p0_+1) into sm0/sm1/smt; tl_ in 0..511
#define LOADPAIRH(p0_, tl_) do {                                                   \
    const int ll_  = (tl_) & 63;                                                   \
    const int wvl_ = (tl_) >> 6;                                                   \
    const int pxg_ = ph * 64 + ll_ - 1;                                            \
    const bool okpx_ = (unsigned)pxg_ < 128u;                                      \
    _Pragma("unroll")                                                              \
    for (int j_ = 0; j_ < 2; ++j_) {                                               \
        const int grow_ = R0 + (p0_) + j_ - 1;                                     \
        const bool ok_ = okpx_ && ((unsigned)grow_ < 128u);                        \
        const float* xs_ = xb + ((size_t)(wvl_ * 8) * HH + grow_) * WW + pxg_;     \
        float* dst_ = j_ ? sm1 : sm0;                                              \
        _Pragma("unroll")                                                          \
        for (int jj_ = 0; jj_ < 8; ++jj_) {                                        \
            float v_ = 0.f;                                                        \
            if (ok_) v_ = xs_[(size_t)jj_ * (HH * WW)];                            \
            dst_[jj_] = v_;                                                        \
        }                                                                          \
    }                                                                              \
    {   /* tail: local px 64,65 for both rows; tl_ 0..31 */                        \
        const int lr_ = ((tl_) >> 4) & 1;                                          \
        const int cc_ = ((tl_) >> 1) & 7;                                          \
        const int pxl_ = 64 + ((tl_) & 1);                                         \
        const int pxg2_ = ph * 64 + pxl_ - 1;                                      \
        const int grow_ = R0 + (p0_) + lr_ - 1;                                    \
        const bool ok_ = ((tl_) < 32) && ((unsigned)pxg2_ < 128u)                  \
                         && ((unsigned)grow_ < 128u);                              \
        const float* xs_ = xb + ((size_t)(cc_ * 8) * HH + grow_) * WW + pxg2_;     \
        _Pragma("unroll")                                                          \
        for (int jj_ = 0; jj_ < 8; ++jj_) {                                        \
            float v_ = 0.f;                                                        \
            if (ok_) v_ = xs_[(size_t)jj_ * (HH * WW)];                            \
            smt[jj_] = v_;                                                         \
        }                                                                          \
    }                                                                              \
} while (0)

// convert + swizzled ds_write into ring slots sA_, sB_; tl_ in 0..511
#define WRITEPAIRH(sA_, sB_, tl_) do {                                             \
    const int ll_  = (tl_) & 63;                                                   \
    const int wvl_ = (tl_) >> 6;                                                   \
    bf16x8 u_;                                                                     \
    _Pragma("unroll")                                                              \
    for (int jj_ = 0; jj_ < 8; ++jj_) u_[jj_] = (__bf16)sm0[jj_];                  \
    *(bf16x8*)(LDS + RING + (sA_) * SLOTB + ll_ * 128                              \
               + ((wvl_ ^ (ll_ & 7)) << 4)) = u_;                                  \
    _Pragma("unroll")                                                              \
    for (int jj_ = 0; jj_ < 8; ++jj_) u_[jj_] = (__bf16)sm1[jj_];                  \
    *(bf16x8*)(LDS + RING + (sB_) * SLOTB + ll_ * 128                              \
               + ((wvl_ ^ (ll_ & 7)) << 4)) = u_;                                  \
    if ((tl_) < 32) {                                                              \
        const int lr_ = ((tl_) >> 4) & 1;                                          \
        const int cc_ = ((tl_) >> 1) & 7;                                          \
        const int pxl_ = 64 + ((tl_) & 1);                                         \
        const int sl_ = lr_ ? (sB_) : (sA_);                                       \
        _Pragma("unroll")                                                          \
        for (int jj_ = 0; jj_ < 8; ++jj_) u_[jj_] = (__bf16)smt[jj_];              \
        *(bf16x8*)(LDS + RING + sl_ * SLOTB + pxl_ * 128                           \
                   + ((cc_ ^ (pxl_ & 7)) << 4)) = u_;                              \
    }                                                                              \
} while (0)

__global__ __launch_bounds__(1024, 1)
void conv_fused(const float* __restrict__ x, const __bf16* __restrict__ wT,
                const float* __restrict__ bias, float* __restrict__ y) {
    __shared__ __align__(16) char LDS[LDSZ];

    // bijective XCD swizzle: blocks of one batch share an XCD
    const int hwid = blockIdx.x;
    const int work = (hwid & 7) * 32 + (hwid >> 3);
    const int b  = work >> 3;
    const int r3 = work & 7;
    const int ph = r3 >> 2;                // px half (64 px)
    const int rg = r3 & 3;                 // 32-row group
    const int R0 = rg * 32;

    const int t  = threadIdx.x;
    const int w  = t >> 6;                 // wave 0..15
    const int l  = t & 63;
    const int lm = l & 15;
    const int lk = l >> 4;
    const int oh = w >> 3;                 // o half (32 o, 2 mf)
    const int w7 = w & 7;
    const int r  = w7 >> 1;                // row within phase (0..3)
    const int q  = w7 & 1;                 // px 32-group within 64

    const __bf16* wb = wT + (size_t)b * 9 * OO * II;
    const float*  xb = x + (size_t)b * II * HH * WW;

    const int obase0 = oh * 32 + lm;       // lane's A row for mf=0

    // ---- prologue: stage A (4608 chunks, source-swizzled) ----
#pragma unroll
    for (int it = 0; it < 5; ++it) {
        const int gbase = it * 1024 + (t & 960);       // wave-uniform base
        if (gbase < 4608) {
            const int cid = it * 1024 + t;
            const int kl  = cid >> 9;
            const int rem = cid & 511;
            const int o   = rem >> 3;
            const int c   = rem & 7;
            const __bf16* src = wb + ((kl * 64 + o) << 6) + ((c ^ (o & 7)) << 3);
            __builtin_amdgcn_global_load_lds((g_u8*)src,
                (lds_u8*)(LDS + (size_t)gbase * 16), 16, 0, 0);
        }
    }

    float sm0[8], sm1[8], smt[8];

    // initial x staging: prows 0..5 into slots 0..5 (halves work in parallel)
    if (t < 512) {
        LOADPAIRH(0, t);
        WRITEPAIRH(0, 1, t);
        LOADPAIRH(4, t);
        WRITEPAIRH(4, 5, t);
    } else {
        LOADPAIRH(2, t - 512);
        WRITEPAIRH(2, 3, t - 512);
    }

    // bias preload
    float bbias[2][4];
    {
        const float* bp = bias + b * OO;
#pragma unroll
        for (int mf = 0; mf < 2; ++mf)
#pragma unroll
            for (int rr = 0; rr < 4; ++rr)
                bbias[mf][rr] = bp[oh * 32 + mf * 16 + lk * 4 + rr];
    }
    f32x4 acc[2][2];
#pragma unroll
    for (int mf = 0; mf < 2; ++mf)
#pragma unroll
        for (int nf = 0; nf < 2; ++nf)
#pragma unroll
            for (int rr = 0; rr < 4; ++rr)
                acc[mf][nf][rr] = bbias[mf][rr];

    __syncthreads();                       // A + prows 0..5 landed

    int s0 = 0;                            // slot of prow 4p

    for (int p = 0; p < 8; ++p) {
        // wave's 3 read-slot byte offsets (runtime values, STATIC dr index)
        int d0_ = s0 + r;  if (d0_ >= NSLOT) d0_ -= NSLOT;
        int d1_ = d0_ + 1; if (d1_ >= NSLOT) d1_ -= NSLOT;
        int d2_ = d1_ + 1; if (d2_ >= NSLOT) d2_ -= NSLOT;
        const int o3[3] = { RING + d0_ * SLOTB, RING + d1_ * SLOTB,
                            RING + d2_ * SLOTB };
        // staging slots for prows 4p+6..4p+9
        int wA = s0 + 6; if (wA >= NSLOT) wA -= NSLOT;
        int wB = wA + 1; if (wB >= NSLOT) wB -= NSLOT;
        int wC = wB + 1; if (wC >= NSLOT) wC -= NSLOT;
        int wD = wC + 1; if (wD >= NSLOT) wD -= NSLOT;

        if (p < 7) {                       // issue next phase's global loads
            if (t < 512) LOADPAIRH(4 * p + 6, t);
            else         LOADPAIRH(4 * p + 8, t - 512);
        }

#pragma unroll
        for (int ks = 0; ks < 18; ++ks) {
            const int kl = ks >> 1, k0 = ks & 1;
            const int dr = kl / 3, dc = kl - 3 * dr;
            const int cc = lk + 4 * k0;
            bf16x8 af[2], bv[2];
#pragma unroll
            for (int mf = 0; mf < 2; ++mf)
                af[mf] = *(const bf16x8*)(LDS + kl * 8192
                         + (obase0 + mf * 16) * 128 + ((cc ^ (lm & 7)) << 4));
#pragma unroll
            for (int nf = 0; nf < 2; ++nf) {
                const int lpx = q * 32 + nf * 16 + lm + dc;
                bv[nf] = *(const bf16x8*)(LDS + o3[dr] + lpx * 128
                         + ((cc ^ (lpx & 7)) << 4));
            }
#pragma unroll
            for (int mf = 0; mf < 2; ++mf)
#pragma unroll
                for (int nf = 0; nf < 2; ++nf)
                    acc[mf][nf] = __builtin_amdgcn_mfma_f32_16x16x32_bf16(
                        af[mf], bv[nf], acc[mf][nf], 0, 0, 0);
        }

        if (p < 7) {                       // land the staged pairs
            if (t < 512) WRITEPAIRH(wA, wB, t);
            else         WRITEPAIRH(wC, wD, t - 512);
        }

        __syncthreads();                   // ring rotated; next rows visible

        // stores + acc reinit
        const int row = R0 + 4 * p + r;
#pragma unroll
        for (int mf = 0; mf < 2; ++mf)
#pragma unroll
            for (int rr = 0; rr < 4; ++rr) {
                const int o = oh * 32 + mf * 16 + lk * 4 + rr;
#pragma unroll
                for (int nf = 0; nf < 2; ++nf) {
                    const int col = ph * 64 + q * 32 + nf * 16 + lm;
                    y[(((size_t)b * OO + o) * HH + row) * WW + col]
                        = acc[mf][nf][rr];
                }
            }
#pragma unroll
        for (int mf = 0; mf < 2; ++mf)
#pragma unroll
            for (int nf = 0; nf < 2; ++nf)
#pragma unroll
                for (int rr = 0; rr < 4; ++rr)
                    acc[mf][nf][rr] = bbias[mf][rr];

        s0 += 4; if (s0 >= NSLOT) s0 -= NSLOT;
    }
}

extern "C" void kernel_launch(void* const* d_in, const int* in_sizes, int n_in,
                              void* d_out, int out_size, void* d_ws, size_t ws_size,
                              hipStream_t stream) {
    const float* addresses = (const float*)d_in[0];   // (B,O,I+1,F)
    const float* x         = (const float*)d_in[1];   // (B,I,H,W)
    const float* w_bank    = (const float*)d_in[2];   // (F,3,3)
    const float* b_bank    = (const float*)d_in[3];   // (F,)
    float* out = (float*)d_out;                       // (B,O,H,W)

    // ws layout: [bias 8KB][wT 2.25MB]
    float*  bias_ws = (float*)d_ws;
    __bf16* wT      = (__bf16*)((char*)d_ws + 8192);

    gen_weights<<<BB * OO, 64, 0, stream>>>(addresses, w_bank, b_bank, wT, bias_ws);
    conv_fused<<<256, 1024, 0, stream>>>(x, wT, bias_ws, out);
}